// Round 2
// baseline (526.499 us; speedup 1.0000x reference)
//
#include <hip/hip_runtime.h>
#include <hip/hip_bf16.h>

typedef __attribute__((ext_vector_type(8))) short short8;
typedef __attribute__((ext_vector_type(4))) float f32x4;

constexpr int T    = 60;    // driven timesteps
constexpr int C    = 128;   // channels == hidden
constexpr int NPIX = 4096;  // samples
constexpr int H    = 128;
constexpr int GP   = 5;
constexpr int EXTRA = T - GP - 1;   // 54 autoregressive steps
constexpr int TT    = T + EXTRA;    // 114 total outputs
constexpr int LDS_STRIDE = 136;     // bf16 elems/row: 272 B, 16B-aligned
constexpr int BUFE = 16 * LDS_STRIDE;  // elems per LDS buffer (4352 B)

__device__ __forceinline__ unsigned short f2bf(float f) {
  unsigned u = __float_as_uint(f);
  u += 0x7FFF + ((u >> 16) & 1);   // round-to-nearest-even
  return (unsigned short)(u >> 16);
}
__device__ __forceinline__ float bf2f(unsigned short s) {
  return __uint_as_float(((unsigned)s) << 16);
}
__device__ __forceinline__ float fast_sigmoid(float x) {
  float e = __builtin_amdgcn_exp2f(-1.44269504f * x);
  return __builtin_amdgcn_rcpf(1.0f + e);
}
__device__ __forceinline__ float fast_tanh(float x) {
  float e = __builtin_amdgcn_exp2f(2.88539008f * x);   // exp(2x)
  return 1.0f - 2.0f * __builtin_amdgcn_rcpf(1.0f + e);
}

// LDS-only barrier: all cross-wave traffic in this kernel is through LDS
// (h/x tiles). Output stores are write-only, x-prefetch loads are consumed
// via compiler-counted vmcnt at their use. So we only drain lgkmcnt —
// __syncthreads()'s vmcnt(0) drain (store-ack + prefetch) stays OFF the
// per-step critical path. sched_barrier(0) pins code motion (rule #18).
__device__ __forceinline__ void wg_barrier() {
  asm volatile("s_waitcnt lgkmcnt(0)" ::: "memory");
  __builtin_amdgcn_s_barrier();
  __builtin_amdgcn_sched_barrier(0);
}

// One WG owns 16 samples, runs all 114 steps. 8 waves; wave w owns gate
// columns {nt*128 + 16w .. +15}. Weights live in VGPRs as bf16 B-fragments.
// xs/hs are DOUBLE-BUFFERED: step t reads buf p, writes buf p^1 -> only ONE
// barrier per step (write-after-read hazard gone; barrier publishes writes).
__global__ __launch_bounds__(512, 2) void lstm_persistent(
    const float* __restrict__ img,   // [T][C][NPIX]
    const float* __restrict__ wih,   // [4H][C]
    const float* __restrict__ whh,   // [4H][H]
    const float* __restrict__ bih,
    const float* __restrict__ bhh,
    float* __restrict__ out)         // [NPIX][TT][H]
{
  __shared__ __align__(16) unsigned short xs[2 * BUFE];
  __shared__ __align__(16) unsigned short hs[2 * BUFE];

  const int tid  = threadIdx.x;
  const int lane = tid & 63;
  const int w    = tid >> 6;      // wave 0..7
  const int l15  = lane & 15;
  const int quad = lane >> 4;     // 0..3
  const int n0   = blockIdx.x * 16;
  const int hid  = w * 16 + l15;  // hidden column this lane owns

  // ---- weight fragments (B-operand: lane holds B[k=quad*8+j][n=l15]) ----
  short8 fih[4][4], fhh[4][4];
  float bias[4];
  #pragma unroll
  for (int nt = 0; nt < 4; ++nt) {
    const int col = nt * 128 + hid;
    bias[nt] = bih[col] + bhh[col];
    #pragma unroll
    for (int kt = 0; kt < 4; ++kt) {
      const int k0 = kt * 32 + quad * 8;
      const float* pih = wih + col * C + k0;
      const float* phh = whh + col * C + k0;
      short8 a, b;
      #pragma unroll
      for (int j = 0; j < 8; ++j) {
        a[j] = (short)f2bf(pih[j]);
        b[j] = (short)f2bf(phh[j]);
      }
      fih[nt][kt] = a;
      fhh[nt][kt] = b;
    }
  }

  // zero h state in buffer 0
  for (int i = tid; i < BUFE; i += 512) hs[i] = 0;

  // fp32 cell state: lane owns (sample = quad*4 + r, hid)
  float c[4] = {0.f, 0.f, 0.f, 0.f};

  // x staging: thread covers (nl = tid&15, channels cb..cb+3)
  const int nl = tid & 15;
  const int cb = (tid >> 4) * 4;
  const float* xbase = img + (size_t)cb * NPIX + n0 + nl;

  auto loadx = [&](int t) -> f32x4 {
    const float* p = xbase + (size_t)t * (C * NPIX);
    return (f32x4){p[0], p[NPIX], p[2 * NPIX], p[3 * NPIX]};
  };

  // stage x_0 into buf0
  {
    f32x4 q = loadx(0);
    ushort4 pk;
    pk.x = f2bf(q[0]); pk.y = f2bf(q[1]); pk.z = f2bf(q[2]); pk.w = f2bf(q[3]);
    *(ushort4*)&xs[nl * LDS_STRIDE + cb] = pk;
  }
  f32x4 qcur = loadx(1);   // in flight across step 0
  wg_barrier();

  const int fro = l15 * LDS_STRIDE + quad * 8;  // A-frag element offset
  float* ob = out + (size_t)(n0 + quad * 4) * (TT * H) + hid;
  const size_t obs = (size_t)TT * H;            // out sample stride

  // one driven step: read buf so, write buf dso; consume qx into xs[dso] if wx
  auto step_drv = [&](int so, int dso, bool wx, f32x4 qx) {
    f32x4 acc[4];
    #pragma unroll
    for (int nt = 0; nt < 4; ++nt)
      acc[nt] = (f32x4){bias[nt], bias[nt], bias[nt], bias[nt]};
    #pragma unroll
    for (int kt = 0; kt < 4; ++kt) {
      short8 ax = *(const short8*)&xs[so + fro + kt * 32];
      short8 ah = *(const short8*)&hs[so + fro + kt * 32];
      #pragma unroll
      for (int nt = 0; nt < 4; ++nt) {
        acc[nt] = __builtin_amdgcn_mfma_f32_16x16x32_bf16(ax, fih[nt][kt], acc[nt], 0, 0, 0);
        acc[nt] = __builtin_amdgcn_mfma_f32_16x16x32_bf16(ah, fhh[nt][kt], acc[nt], 0, 0, 0);
      }
    }
    // publish next x tile (counted vmcnt wait on qx lands here, ~1.5 steps
    // after issue -> fully covered)
    if (wx) {
      ushort4 pk;
      pk.x = f2bf(qx[0]); pk.y = f2bf(qx[1]); pk.z = f2bf(qx[2]); pk.w = f2bf(qx[3]);
      *(ushort4*)&xs[dso + nl * LDS_STRIDE + cb] = pk;
    }
    float hv[4];
    #pragma unroll
    for (int r = 0; r < 4; ++r) {
      float ig = fast_sigmoid(acc[0][r]);
      float fg = fast_sigmoid(acc[1][r]);
      float gg = fast_tanh(acc[2][r]);
      float og = fast_sigmoid(acc[3][r]);
      c[r] = fg * c[r] + ig * gg;
      hv[r] = og * fast_tanh(c[r]);
    }
    #pragma unroll
    for (int r = 0; r < 4; ++r)
      hs[dso + (quad * 4 + r) * LDS_STRIDE + hid] = f2bf(hv[r]);
    #pragma unroll
    for (int r = 0; r < 4; ++r)
      __builtin_nontemporal_store(hv[r], ob + (size_t)r * obs);  // never waited in-loop
    ob += H;
    wg_barrier();
  };

  // one AR step: h feeds back as x; fih holds folded (Wih+Whh) by then
  auto step_ar = [&](int so, int dso) {
    f32x4 acc[4];
    #pragma unroll
    for (int nt = 0; nt < 4; ++nt)
      acc[nt] = (f32x4){bias[nt], bias[nt], bias[nt], bias[nt]};
    #pragma unroll
    for (int kt = 0; kt < 4; ++kt) {
      short8 ah = *(const short8*)&hs[so + fro + kt * 32];
      #pragma unroll
      for (int nt = 0; nt < 4; ++nt)
        acc[nt] = __builtin_amdgcn_mfma_f32_16x16x32_bf16(ah, fih[nt][kt], acc[nt], 0, 0, 0);
    }
    float hv[4];
    #pragma unroll
    for (int r = 0; r < 4; ++r) {
      float ig = fast_sigmoid(acc[0][r]);
      float fg = fast_sigmoid(acc[1][r]);
      float gg = fast_tanh(acc[2][r]);
      float og = fast_sigmoid(acc[3][r]);
      c[r] = fg * c[r] + ig * gg;
      hv[r] = og * fast_tanh(c[r]);
    }
    #pragma unroll
    for (int r = 0; r < 4; ++r)
      hs[dso + (quad * 4 + r) * LDS_STRIDE + hid] = f2bf(hv[r]);
    #pragma unroll
    for (int r = 0; r < 4; ++r)
      __builtin_nontemporal_store(hv[r], ob + (size_t)r * obs);
    ob += H;
    wg_barrier();
  };

  // ---- driven phase: 60 steps, 2x unrolled (even parity), prefetch depth
  // ~1.5 steps. In iteration t: stepA reads x_t from buf0, publishes
  // x_{t+1}; stepB reads x_{t+1} from buf1, publishes x_{t+2}. ----
  #pragma unroll 1
  for (int t = 0; t < T - 4; t += 2) {      // t = 0,2,..,54 -> steps 0..55
    f32x4 qA = loadx(t + 2);
    step_drv(0, BUFE, true, qcur);
    f32x4 qB = loadx(t + 3);
    step_drv(BUFE, 0, true, qA);
    qcur = qB;
  }
  {                                          // steps 56,57
    f32x4 qA = loadx(58);
    step_drv(0, BUFE, true, qcur);           // reads x56, publishes x57
    f32x4 qB = loadx(59);
    step_drv(BUFE, 0, true, qA);             // reads x57, publishes x58
    qcur = qB;
  }
  {                                          // steps 58,59
    step_drv(0, BUFE, true, qcur);           // reads x58, publishes x59
    step_drv(BUFE, 0, false, qcur);          // reads x59; no x publish
  }

  // ---- fold W_sum = W_ih + W_hh into fih (registers only, no sync needed) ----
  #pragma unroll
  for (int nt = 0; nt < 4; ++nt)
    #pragma unroll
    for (int kt = 0; kt < 4; ++kt) {
      short8 a = fih[nt][kt], b = fhh[nt][kt];
      #pragma unroll
      for (int j = 0; j < 8; ++j)
        a[j] = (short)f2bf(bf2f((unsigned short)a[j]) + bf2f((unsigned short)b[j]));
      fih[nt][kt] = a;
    }

  // ---- AR phase: 54 steps, 2x unrolled; h state currently in buf0 ----
  #pragma unroll 1
  for (int t = 0; t < EXTRA; t += 2) {
    step_ar(0, BUFE);
    step_ar(BUFE, 0);
  }
}

extern "C" void kernel_launch(void* const* d_in, const int* in_sizes, int n_in,
                              void* d_out, int out_size, void* d_ws, size_t ws_size,
                              hipStream_t stream) {
  (void)in_sizes; (void)n_in; (void)d_ws; (void)ws_size; (void)out_size;
  const float* img = (const float*)d_in[0];
  // d_in[1] = mask (unused by reference forward)
  const float* wih = (const float*)d_in[2];
  const float* whh = (const float*)d_in[3];
  const float* bih = (const float*)d_in[4];
  const float* bhh = (const float*)d_in[5];
  // d_in[6] = gp_affected_timesteps (static = 5, baked into EXTRA)
  float* out = (float*)d_out;

  lstm_persistent<<<NPIX / 16, 512, 0, stream>>>(img, wih, whh, bih, bhh, out);
}

// Round 3
// 524.987 us; speedup vs baseline: 1.0029x; 1.0029x over previous
//
#include <hip/hip_runtime.h>
#include <hip/hip_bf16.h>

typedef __attribute__((ext_vector_type(8))) short short8;
typedef __attribute__((ext_vector_type(4))) float f32x4;

constexpr int T    = 60;    // driven timesteps
constexpr int C    = 128;   // channels == hidden
constexpr int NPIX = 4096;  // samples
constexpr int H    = 128;
constexpr int GP   = 5;
constexpr int EXTRA = T - GP - 1;   // 54 autoregressive steps
constexpr int TT    = T + EXTRA;    // 114 total outputs
constexpr int LDS_STRIDE = 136;     // bf16 elems/row: 272 B, 16B-aligned
constexpr int BUFE = 16 * LDS_STRIDE;  // elems per LDS buffer (4352 B)
constexpr int OS_STRIDE = 132;      // fp32 out-staging row stride (breaks banks)
constexpr int OSB = 16 * OS_STRIDE; // floats per out-staging buffer

__device__ __forceinline__ unsigned short f2bf(float f) {
  unsigned u = __float_as_uint(f);
  u += 0x7FFF + ((u >> 16) & 1);   // round-to-nearest-even
  return (unsigned short)(u >> 16);
}
__device__ __forceinline__ float bf2f(unsigned short s) {
  return __uint_as_float(((unsigned)s) << 16);
}
__device__ __forceinline__ float fast_sigmoid(float x) {
  float e = __builtin_amdgcn_exp2f(-1.44269504f * x);
  return __builtin_amdgcn_rcpf(1.0f + e);
}
__device__ __forceinline__ float fast_tanh(float x) {
  float e = __builtin_amdgcn_exp2f(2.88539008f * x);   // exp(2x)
  return 1.0f - 2.0f * __builtin_amdgcn_rcpf(1.0f + e);
}

// LDS-only barrier: all cross-wave traffic is through LDS. Output stores are
// full-line fire-and-forget, x-prefetch loads are consumed via counted vmcnt
// at their use — so only lgkmcnt is drained; vmcnt(0) stays OFF the per-step
// critical path. sched_barrier(0) pins code motion (rule #18).
__device__ __forceinline__ void wg_barrier() {
  asm volatile("s_waitcnt lgkmcnt(0)" ::: "memory");
  __builtin_amdgcn_s_barrier();
  __builtin_amdgcn_sched_barrier(0);
}

// One WG owns 16 samples, runs all 114 steps. 8 waves; wave w owns gate
// columns {nt*128 + 16w .. +15}. Weights live in VGPRs as bf16 B-fragments.
// xs/hs double-buffered -> one barrier per step. Output goes through an fp32
// LDS staging tile (os, double-buffered) and is stored as FULL 128-B lines
// (512 B contiguous per sample row, float4/lane) — partial-line RMW
// amplification (round-2 regression: WRITE 488 MB vs 239 ideal) eliminated.
__global__ __launch_bounds__(512, 2) void lstm_persistent(
    const float* __restrict__ img,   // [T][C][NPIX]
    const float* __restrict__ wih,   // [4H][C]
    const float* __restrict__ whh,   // [4H][H]
    const float* __restrict__ bih,
    const float* __restrict__ bhh,
    float* __restrict__ out)         // [NPIX][TT][H]
{
  __shared__ __align__(16) unsigned short xs[2 * BUFE];
  __shared__ __align__(16) unsigned short hs[2 * BUFE];
  __shared__ __align__(16) float os[2 * OSB];

  const int tid  = threadIdx.x;
  const int lane = tid & 63;
  const int w    = tid >> 6;      // wave 0..7
  const int l15  = lane & 15;
  const int quad = lane >> 4;     // 0..3
  // XCD swizzle (bijective, 256 WGs = 8 XCDs * 32): hw-consecutive blocks
  // round-robin XCDs; remap so logical neighbors (which SHARE img cache
  // lines: 128 B = 32 samples = 2 WGs) land on the same XCD's L2.
  const int lb   = ((int)blockIdx.x & 7) * 32 + ((int)blockIdx.x >> 3);
  const int n0   = lb * 16;
  const int hid  = w * 16 + l15;  // hidden column this lane owns

  // ---- weight fragments (B-operand: lane holds B[k=quad*8+j][n=l15]) ----
  short8 fih[4][4], fhh[4][4];
  float bias[4];
  #pragma unroll
  for (int nt = 0; nt < 4; ++nt) {
    const int col = nt * 128 + hid;
    bias[nt] = bih[col] + bhh[col];
    #pragma unroll
    for (int kt = 0; kt < 4; ++kt) {
      const int k0 = kt * 32 + quad * 8;
      const float* pih = wih + col * C + k0;
      const float* phh = whh + col * C + k0;
      short8 a, b;
      #pragma unroll
      for (int j = 0; j < 8; ++j) {
        a[j] = (short)f2bf(pih[j]);
        b[j] = (short)f2bf(phh[j]);
      }
      fih[nt][kt] = a;
      fhh[nt][kt] = b;
    }
  }

  // zero h state in buffer 0
  for (int i = tid; i < BUFE; i += 512) hs[i] = 0;

  // fp32 cell state: lane owns (sample = quad*4 + r, hid)
  float c[4] = {0.f, 0.f, 0.f, 0.f};

  // x staging: thread covers (nl = tid&15, channels cb..cb+3)
  const int nl = tid & 15;
  const int cb = (tid >> 4) * 4;
  const float* xbase = img + (size_t)cb * NPIX + n0 + nl;

  auto loadx = [&](int t) -> f32x4 {
    const float* p = xbase + (size_t)t * (C * NPIX);
    return (f32x4){p[0], p[NPIX], p[2 * NPIX], p[3 * NPIX]};
  };

  // stage x_0 into buf0
  {
    f32x4 q = loadx(0);
    ushort4 pk;
    pk.x = f2bf(q[0]); pk.y = f2bf(q[1]); pk.z = f2bf(q[2]); pk.w = f2bf(q[3]);
    *(ushort4*)&xs[nl * LDS_STRIDE + cb] = pk;
  }
  f32x4 qcur = loadx(1);   // in flight across step 0
  wg_barrier();

  const int fro = l15 * LDS_STRIDE + quad * 8;  // A-frag element offset

  // coalesced out-store mapping: thread covers (sample ss, cols c4..c4+3);
  // 32 consecutive lanes write 512 B contiguous = 4 FULL 128-B lines.
  const int ss = tid >> 5;          // sample 0..15
  const int c4 = (tid & 31) * 4;    // hid column 0,4,..,124
  const size_t obs = (size_t)TT * H;
  float* osp = out + (size_t)(n0 + ss) * obs + c4;   // advances by H per step

  // one driven step: read bufs at so, write bufs at dso (and os at oso);
  // consume qx into xs[dso] if wx
  auto step_drv = [&](int so, int dso, int oso, bool wx, f32x4 qx) {
    f32x4 acc[4];
    #pragma unroll
    for (int nt = 0; nt < 4; ++nt)
      acc[nt] = (f32x4){bias[nt], bias[nt], bias[nt], bias[nt]};
    #pragma unroll
    for (int kt = 0; kt < 4; ++kt) {
      short8 ax = *(const short8*)&xs[so + fro + kt * 32];
      short8 ah = *(const short8*)&hs[so + fro + kt * 32];
      #pragma unroll
      for (int nt = 0; nt < 4; ++nt) {
        acc[nt] = __builtin_amdgcn_mfma_f32_16x16x32_bf16(ax, fih[nt][kt], acc[nt], 0, 0, 0);
        acc[nt] = __builtin_amdgcn_mfma_f32_16x16x32_bf16(ah, fhh[nt][kt], acc[nt], 0, 0, 0);
      }
    }
    // publish next x tile (counted vmcnt wait on qx lands here)
    if (wx) {
      ushort4 pk;
      pk.x = f2bf(qx[0]); pk.y = f2bf(qx[1]); pk.z = f2bf(qx[2]); pk.w = f2bf(qx[3]);
      *(ushort4*)&xs[dso + nl * LDS_STRIDE + cb] = pk;
    }
    float hv[4];
    #pragma unroll
    for (int r = 0; r < 4; ++r) {
      float ig = fast_sigmoid(acc[0][r]);
      float fg = fast_sigmoid(acc[1][r]);
      float gg = fast_tanh(acc[2][r]);
      float og = fast_sigmoid(acc[3][r]);
      c[r] = fg * c[r] + ig * gg;
      hv[r] = og * fast_tanh(c[r]);
    }
    #pragma unroll
    for (int r = 0; r < 4; ++r) {
      hs[dso + (quad * 4 + r) * LDS_STRIDE + hid] = f2bf(hv[r]);
      os[oso + (quad * 4 + r) * OS_STRIDE + hid] = hv[r];
    }
    wg_barrier();
    // coalesced full-line out store from staged tile (fire-and-forget)
    {
      f32x4 v = *(const f32x4*)&os[oso + ss * OS_STRIDE + c4];
      __builtin_nontemporal_store(v, (f32x4*)osp);
      osp += H;
    }
  };

  // one AR step: h feeds back as x; fih holds folded (Wih+Whh) by then
  auto step_ar = [&](int so, int dso, int oso) {
    f32x4 acc[4];
    #pragma unroll
    for (int nt = 0; nt < 4; ++nt)
      acc[nt] = (f32x4){bias[nt], bias[nt], bias[nt], bias[nt]};
    #pragma unroll
    for (int kt = 0; kt < 4; ++kt) {
      short8 ah = *(const short8*)&hs[so + fro + kt * 32];
      #pragma unroll
      for (int nt = 0; nt < 4; ++nt)
        acc[nt] = __builtin_amdgcn_mfma_f32_16x16x32_bf16(ah, fih[nt][kt], acc[nt], 0, 0, 0);
    }
    float hv[4];
    #pragma unroll
    for (int r = 0; r < 4; ++r) {
      float ig = fast_sigmoid(acc[0][r]);
      float fg = fast_sigmoid(acc[1][r]);
      float gg = fast_tanh(acc[2][r]);
      float og = fast_sigmoid(acc[3][r]);
      c[r] = fg * c[r] + ig * gg;
      hv[r] = og * fast_tanh(c[r]);
    }
    #pragma unroll
    for (int r = 0; r < 4; ++r) {
      hs[dso + (quad * 4 + r) * LDS_STRIDE + hid] = f2bf(hv[r]);
      os[oso + (quad * 4 + r) * OS_STRIDE + hid] = hv[r];
    }
    wg_barrier();
    {
      f32x4 v = *(const f32x4*)&os[oso + ss * OS_STRIDE + c4];
      __builtin_nontemporal_store(v, (f32x4*)osp);
      osp += H;
    }
  };

  // ---- driven phase: 60 steps, 2x unrolled, prefetch depth ~1.5 steps.
  // stepA reads x_t from buf0, publishes x_{t+1}; stepB reads x_{t+1} from
  // buf1, publishes x_{t+2}. ----
  #pragma unroll 1
  for (int t = 0; t < T - 4; t += 2) {      // t = 0,2,..,54 -> steps 0..55
    f32x4 qA = loadx(t + 2);
    step_drv(0, BUFE, OSB, true, qcur);
    f32x4 qB = loadx(t + 3);
    step_drv(BUFE, 0, 0, true, qA);
    qcur = qB;
  }
  {                                          // steps 56,57
    f32x4 qA = loadx(58);
    step_drv(0, BUFE, OSB, true, qcur);      // reads x56, publishes x57
    f32x4 qB = loadx(59);
    step_drv(BUFE, 0, 0, true, qA);          // reads x57, publishes x58
    qcur = qB;
  }
  {                                          // steps 58,59
    step_drv(0, BUFE, OSB, true, qcur);      // reads x58, publishes x59
    step_drv(BUFE, 0, 0, false, qcur);       // reads x59; no x publish
  }

  // ---- fold W_sum = W_ih + W_hh into fih (registers only, no sync needed) ----
  #pragma unroll
  for (int nt = 0; nt < 4; ++nt)
    #pragma unroll
    for (int kt = 0; kt < 4; ++kt) {
      short8 a = fih[nt][kt], b = fhh[nt][kt];
      #pragma unroll
      for (int j = 0; j < 8; ++j)
        a[j] = (short)f2bf(bf2f((unsigned short)a[j]) + bf2f((unsigned short)b[j]));
      fih[nt][kt] = a;
    }

  // ---- AR phase: 54 steps, 2x unrolled; h state currently in buf0 ----
  #pragma unroll 1
  for (int t = 0; t < EXTRA; t += 2) {
    step_ar(0, BUFE, OSB);
    step_ar(BUFE, 0, 0);
  }
}

extern "C" void kernel_launch(void* const* d_in, const int* in_sizes, int n_in,
                              void* d_out, int out_size, void* d_ws, size_t ws_size,
                              hipStream_t stream) {
  (void)in_sizes; (void)n_in; (void)d_ws; (void)ws_size; (void)out_size;
  const float* img = (const float*)d_in[0];
  // d_in[1] = mask (unused by reference forward)
  const float* wih = (const float*)d_in[2];
  const float* whh = (const float*)d_in[3];
  const float* bih = (const float*)d_in[4];
  const float* bhh = (const float*)d_in[5];
  // d_in[6] = gp_affected_timesteps (static = 5, baked into EXTRA)
  float* out = (float*)d_out;

  lstm_persistent<<<NPIX / 16, 512, 0, stream>>>(img, wih, whh, bih, bhh, out);
}